// Round 1
// baseline (1813.648 us; speedup 1.0000x reference)
//
#include <hip/hip_runtime.h>

#define NPTS 8192
#define NB   4
#define COUT 64
#define NSC  3

// One 256-thread workgroup per (batch, point) row.
// Phase 1: each thread computes 32 candidate distances (fp64, exact reference
//          formula) into registers, m = t + 256*j (coalesced loads at fixed j).
// Phase 2: 40 rounds of extract-max with (value desc, index asc) tie-break.
//          Per-thread best lives in LDS; wave0 reduces 256 entries per round.
//          Each thread caches its top-2 so a full register rescan only happens
//          when it loses its 2nd candidate (rare).
// Phase 3: fused edge-conv + BN(eval) + LeakyReLU(0.2) + maxpool over the
//          first k_s selected neighbors, threads mapped to (scale, out_ch).
__global__ __launch_bounds__(256) void msedge_kernel(
    const float* __restrict__ x,
    const float* __restrict__ W,
    const float* __restrict__ gamma,
    const float* __restrict__ beta,
    const float* __restrict__ rmean,
    const float* __restrict__ rvar,
    float* __restrict__ out)
{
    const int t = threadIdx.x;
    const int blk = blockIdx.x;
    // bijective XCD swizzle: 32768 blocks = 8 XCDs x 4096 contiguous rows
    const int swz = (blk & 7) * (NB * NPTS / 8) + (blk >> 3);
    const int b = swz >> 13;
    const int n = swz & (NPTS - 1);

    const float* __restrict__ xb = x + b * 3 * NPTS;

    __shared__ double s_val[256];
    __shared__ int    s_idx[256];
    __shared__ int    s_selm[40];
    __shared__ float  s_nb[40][3];
    __shared__ int    s_win;

    const float cx0 = xb[n], cx1 = xb[NPTS + n], cx2 = xb[2 * NPTS + n];
    const double dc0 = cx0, dc1 = cx1, dc2 = cx2;
    const double cxx = dc0 * dc0 + dc1 * dc1 + dc2 * dc2;

    // ---- Phase 1: distances in registers (static indexing via full unroll)
    double dist[32];
#pragma unroll
    for (int j = 0; j < 32; ++j) {
        const int m = t + 256 * j;
        const double p0 = xb[m];
        const double p1 = xb[NPTS + m];
        const double p2 = xb[2 * NPTS + m];
        const double inner = dc0 * p0 + dc1 * p1 + dc2 * p2;
        const double xxm = p0 * p0 + p1 * p1 + p2 * p2;
        dist[j] = 2.0 * inner - cxx - xxm;   // = -||x_n - x_m||^2
    }

    unsigned removed = 0u;

    // initial per-thread top-2 (strict > prefers smaller j => smaller m on ties)
    double v1 = -1e300, v2 = -1e300;
    int j1 = -1, j2 = -1;
#pragma unroll
    for (int j = 0; j < 32; ++j) {
        const double v = dist[j];
        if (v > v1) { v2 = v1; j2 = j1; v1 = v; j1 = j; }
        else if (v > v2) { v2 = v; j2 = j; }
    }
    bool have2 = true;
    s_val[t] = v1;
    s_idx[t] = t + 256 * j1;
    __syncthreads();

    // ---- Phase 2: 40 extract-max rounds
    for (int r = 0; r < 40; ++r) {
        if (t < 64) {
            double bv = s_val[t];
            int    bm = s_idx[t];
#pragma unroll
            for (int q = 1; q < 4; ++q) {
                const double ov = s_val[t + 64 * q];
                const int    om = s_idx[t + 64 * q];
                if (ov > bv || (ov == bv && om < bm)) { bv = ov; bm = om; }
            }
#pragma unroll
            for (int off = 32; off >= 1; off >>= 1) {
                const double ov = __shfl_down(bv, off);
                const int    om = __shfl_down(bm, off);
                if (ov > bv || (ov == bv && om < bm)) { bv = ov; bm = om; }
            }
            if (t == 0) { s_win = bm; s_selm[r] = bm; }
        }
        __syncthreads();
        const int wm = s_win;
        if ((wm & 255) == t) {           // owner thread of the extracted candidate
            removed |= 1u << (wm >> 8);
            if (have2) {                 // promote cached 2nd best
                v1 = v2; j1 = j2;
                have2 = false;
            } else {                     // rare: rebuild top-2 from registers
                v1 = -1e300; v2 = -1e300; j1 = -1; j2 = -1;
#pragma unroll
                for (int j = 0; j < 32; ++j) {
                    const double v = ((removed >> j) & 1u) ? -1e300 : dist[j];
                    if (v > v1) { v2 = v1; j2 = j1; v1 = v; j1 = j; }
                    else if (v > v2) { v2 = v; j2 = j; }
                }
                have2 = true;
            }
            s_val[t] = v1;
            s_idx[t] = t + 256 * j1;
        }
        __syncthreads();
    }

    // ---- Phase 3: gather neighbor coords, fused conv+BN+LeakyReLU+maxpool
    if (t < 40 * 3) {
        const int j = t / 3, c = t % 3;
        s_nb[j][c] = xb[c * NPTS + s_selm[j]];
    }
    __syncthreads();

    if (t < NSC * COUT) {
        const int s = t >> 6;
        const int o = t & 63;
        const float* Wp = W + (s * COUT + o) * 6;
        const float w0 = Wp[0], w1 = Wp[1], w2 = Wp[2];
        const float w3 = Wp[3], w4 = Wp[4], w5 = Wp[5];
        const int go = s * COUT + o;
        const float inv = gamma[go] * (1.0f / sqrtf(rvar[go] + 1e-5f));
        const float sh  = beta[go] - rmean[go] * inv;
        const float base = w3 * cx0 + w4 * cx1 + w5 * cx2;
        const int k = (s == 0) ? 10 : (s == 1) ? 20 : 40;
        float mx = -3.4e38f;
        for (int j = 0; j < k; ++j) {
            const float e0 = s_nb[j][0] - cx0;
            const float e1 = s_nb[j][1] - cx1;
            const float e2 = s_nb[j][2] - cx2;
            float y = w0 * e0 + w1 * e1 + w2 * e2 + base;
            y = y * inv + sh;
            y = (y >= 0.0f) ? y : 0.2f * y;
            mx = fmaxf(mx, y);
        }
        out[((s * NB + b) * COUT + o) * NPTS + n] = mx;
    }
}

extern "C" void kernel_launch(void* const* d_in, const int* in_sizes, int n_in,
                              void* d_out, int out_size, void* d_ws, size_t ws_size,
                              hipStream_t stream) {
    const float* x     = (const float*)d_in[0];
    const float* W     = (const float*)d_in[1];
    const float* gamma = (const float*)d_in[2];
    const float* beta  = (const float*)d_in[3];
    const float* rmean = (const float*)d_in[4];
    const float* rvar  = (const float*)d_in[5];
    float* out = (float*)d_out;

    msedge_kernel<<<dim3(NB * NPTS), dim3(256), 0, stream>>>(
        x, W, gamma, beta, rmean, rvar, out);
}

// Round 2
// 880.433 us; speedup vs baseline: 2.0599x; 2.0599x over previous
//
#include <hip/hip_runtime.h>
#include <float.h>

#define NPTS  8192
#define NB    4
#define COUT  64
#define ROWS  8          // rows per block, one wave each
#define NBINS 1024
#define CAP   256

#define ELEM(v,q) ((q)==0?(v).x:(q)==1?(v).y:(q)==2?(v).z:(v).w)

// Block = 512 threads = 8 waves; wave w owns row (n_base + w).
// Phase A: f32 distance screen -> 1024-bin histogram (per-row, in LDS).
// Scan:    find bin threshold B* with cumulative count >= 40 (from top).
// Phase B: collect candidate indices with d32 >= edge(B*) - 1e-3 (superset
//          of the exact fp64 top-40; f32 abs error <= ~8e-5).
// Exact:   fp64 distance for collected (~70) candidates, all-pairs lex rank
//          (val desc, idx asc) == jax.lax.top_k tie-break; rank<40 selected,
//          rank order gives top-10/20 prefixes for the k=10/20 scales.
// Epilogue: per (out_ch, row) thread: conv(BN-folded) + LeakyReLU + maxpool,
//          stores 32B-coalesced (8 consecutive n per block).
__global__ __launch_bounds__(512) void msedge_kernel(
    const float* __restrict__ x,
    const float* __restrict__ W,
    const float* __restrict__ gamma,
    const float* __restrict__ beta,
    const float* __restrict__ rmean,
    const float* __restrict__ rvar,
    float* __restrict__ out)
{
    __shared__ unsigned hist[ROWS][NBINS];   // 32 KB; reused for packed (d64,idx)
    __shared__ int      col[ROWS][CAP];      // 8 KB
    __shared__ int      ccnt[ROWS];
    __shared__ float4   nbx[ROWS][40];       // 5 KB, neighbor coords by rank

    const int t    = threadIdx.x;
    const int w    = t >> 6;                 // wave id == row-in-block
    const int lane = t & 63;

    const int blk = blockIdx.x;
    const int swz = (blk & 7) * 512 + (blk >> 3);   // bijective XCD swizzle (4096 blocks)
    const int row_base = swz * ROWS;
    const int b      = row_base >> 13;
    const int n_base = row_base & (NPTS - 1);
    const int n      = n_base + w;

    const float* __restrict__ xb = x + b * 3 * NPTS;

    // zero own row's hist + counter (within-wave only)
#pragma unroll
    for (int u = 0; u < NBINS / 64; ++u) hist[w][lane + 64 * u] = 0u;
    if (lane == 0) ccnt[w] = 0;

    const float c0 = xb[n], c1 = xb[NPTS + n], c2 = xb[2 * NPTS + n];
    const float cxx = fmaf(c0, c0, fmaf(c1, c1, c2 * c2));
    const double dc0 = (double)c0, dc1 = (double)c1, dc2 = (double)c2;
    const double dcxx = fma(dc0, dc0, fma(dc1, dc1, dc2 * dc2));

    asm volatile("s_waitcnt lgkmcnt(0)" ::: "memory");

    // ---------------- Phase A: f32 screen histogram ----------------
    const int mbase = lane * 128;
    for (int it = 0; it < 32; ++it) {
        const int m0 = mbase + 4 * it;
        const float4 a0 = *(const float4*)(xb + m0);
        const float4 a1 = *(const float4*)(xb + NPTS + m0);
        const float4 a2 = *(const float4*)(xb + 2 * NPTS + m0);
#pragma unroll
        for (int q = 0; q < 4; ++q) {
            const float p0 = ELEM(a0, q), p1 = ELEM(a1, q), p2 = ELEM(a2, q);
            const float inner = fmaf(c0, p0, fmaf(c1, p1, c2 * p2));
            const float xxm   = fmaf(p0, p0, fmaf(p1, p1, p2 * p2));
            const float d     = fmaf(2.0f, inner, -cxx) - xxm;   // -||pi-pj||^2
            const unsigned u  = __float_as_uint(d);
            const unsigned k  = ((int)u < 0) ? ~u : (u | 0x80000000u);
            atomicAdd(&hist[w][k >> 22], 1u);
        }
    }
    asm volatile("s_waitcnt lgkmcnt(0)" ::: "memory");

    // ---------------- Scan: find threshold bin ----------------
    unsigned tot = 0;
#pragma unroll
    for (int u = 0; u < 16; ++u) tot += hist[w][1023 - (lane * 16 + u)];
    unsigned inc = tot;
#pragma unroll
    for (int off = 1; off < 64; off <<= 1) {
        const unsigned y = __shfl_up(inc, off);
        if (lane >= off) inc += y;
    }
    const unsigned pre = inc - tot;          // count in bins strictly above my chunk
    int mypos = 0x7fffffff;
    if (pre + tot >= 40u) {
        unsigned run = pre;
#pragma unroll
        for (int u = 0; u < 16; ++u) {
            run += hist[w][1023 - (lane * 16 + u)];
            if (run >= 40u && mypos == 0x7fffffff) mypos = lane * 16 + u;
        }
    }
#pragma unroll
    for (int off = 1; off < 64; off <<= 1)
        mypos = min(mypos, __shfl_xor(mypos, off));
    const int Bstar = 1023 - mypos;
    const unsigned k0 = (unsigned)Bstar << 22;
    const unsigned ue = (k0 & 0x80000000u) ? (k0 & 0x7fffffffu) : ~k0;
    const float tau = __uint_as_float(ue) - 1e-3f;

    // ---------------- Phase B: collect superset ----------------
    for (int it = 0; it < 32; ++it) {
        const int m0 = mbase + 4 * it;
        const float4 a0 = *(const float4*)(xb + m0);
        const float4 a1 = *(const float4*)(xb + NPTS + m0);
        const float4 a2 = *(const float4*)(xb + 2 * NPTS + m0);
#pragma unroll
        for (int q = 0; q < 4; ++q) {
            const float p0 = ELEM(a0, q), p1 = ELEM(a1, q), p2 = ELEM(a2, q);
            const float inner = fmaf(c0, p0, fmaf(c1, p1, c2 * p2));
            const float xxm   = fmaf(p0, p0, fmaf(p1, p1, p2 * p2));
            const float d     = fmaf(2.0f, inner, -cxx) - xxm;
            if (d >= tau) {
                const int p = atomicAdd(&ccnt[w], 1);
                if (p < CAP) col[w][p] = m0 + q;
            }
        }
    }
    asm volatile("s_waitcnt lgkmcnt(0)" ::: "memory");
    int C = ccnt[w]; C = min(C, CAP);

    // ---------------- Exact fp64 distances ----------------
    double exd[4]; int exm[4]; float ep0[4], ep1[4], ep2[4];
#pragma unroll
    for (int q = 0; q < 4; ++q) {
        const int i = lane + 64 * q;
        exm[q] = -1;
        if (i < C) {
            const int m = col[w][i];
            const float p0 = xb[m], p1 = xb[NPTS + m], p2 = xb[2 * NPTS + m];
            ep0[q] = p0; ep1[q] = p1; ep2[q] = p2;
            const double P0 = p0, P1 = p1, P2 = p2;
            const double inner = fma(dc0, P0, fma(dc1, P1, dc2 * P2));
            const double xxm   = fma(P0, P0, fma(P1, P1, P2 * P2));
            const double dd    = 2.0 * inner - dcxx - xxm;
            exd[q] = dd; exm[q] = m;
            double2 pk; pk.x = dd; pk.y = __hiloint2double(0, m);
            *(double2*)&hist[w][i * 4] = pk;     // overlay on dead hist
        }
    }
    asm volatile("s_waitcnt lgkmcnt(0)" ::: "memory");

    // ---------------- All-pairs lex rank ----------------
    int myr[4] = {0, 0, 0, 0};
    for (int j = 0; j < C; ++j) {
        const double2 pk = *(const double2*)&hist[w][j * 4];
        const double dv = pk.x;
        const int    mj = __double2loint(pk.y);
#pragma unroll
        for (int q = 0; q < 4; ++q) {
            if (exm[q] >= 0) {
                const bool g = (dv > exd[q]) || (dv == exd[q] && mj < exm[q]);
                myr[q] += g ? 1 : 0;
            }
        }
    }
#pragma unroll
    for (int q = 0; q < 4; ++q)
        if (exm[q] >= 0 && myr[q] < 40)
            nbx[w][myr[q]] = make_float4(ep0[q], ep1[q], ep2[q], 0.0f);

    __syncthreads();

    // ---------------- Fused conv + BN + LeakyReLU + maxpool ----------------
    const int o  = t >> 3;       // 0..63
    const int rr = t & 7;        // row within block
    const int nn = n_base + rr;
    const float cc0 = xb[nn], cc1 = xb[NPTS + nn], cc2 = xb[2 * NPTS + nn];

    float w0_[3], w1_[3], w2_[3], bb[3];
#pragma unroll
    for (int s = 0; s < 3; ++s) {
        const int go = s * COUT + o;
        const float* Wp = W + go * 6;
        const float inv = gamma[go] / sqrtf(rvar[go] + 1e-5f);
        const float sh  = beta[go] - rmean[go] * inv;
        const float base = fmaf(Wp[3], cc0, fmaf(Wp[4], cc1, Wp[5] * cc2));
        w0_[s] = Wp[0] * inv; w1_[s] = Wp[1] * inv; w2_[s] = Wp[2] * inv;
        bb[s]  = fmaf(base, inv, sh);
    }
    float mx0 = -FLT_MAX, mx1 = -FLT_MAX, mx2 = -FLT_MAX;
    for (int j = 0; j < 40; ++j) {
        const float4 v = nbx[rr][j];
        const float e0 = v.x - cc0, e1 = v.y - cc1, e2 = v.z - cc2;
        {
            float y = fmaf(w0_[2], e0, fmaf(w1_[2], e1, fmaf(w2_[2], e2, bb[2])));
            y = fmaxf(y, 0.2f * y); mx2 = fmaxf(mx2, y);
        }
        if (j < 20) {
            float y = fmaf(w0_[1], e0, fmaf(w1_[1], e1, fmaf(w2_[1], e2, bb[1])));
            y = fmaxf(y, 0.2f * y); mx1 = fmaxf(mx1, y);
        }
        if (j < 10) {
            float y = fmaf(w0_[0], e0, fmaf(w1_[0], e1, fmaf(w2_[0], e2, bb[0])));
            y = fmaxf(y, 0.2f * y); mx0 = fmaxf(mx0, y);
        }
    }
    out[((0 * NB + b) * COUT + o) * NPTS + nn] = mx0;
    out[((1 * NB + b) * COUT + o) * NPTS + nn] = mx1;
    out[((2 * NB + b) * COUT + o) * NPTS + nn] = mx2;
}

extern "C" void kernel_launch(void* const* d_in, const int* in_sizes, int n_in,
                              void* d_out, int out_size, void* d_ws, size_t ws_size,
                              hipStream_t stream) {
    const float* x     = (const float*)d_in[0];
    const float* W     = (const float*)d_in[1];
    const float* gamma = (const float*)d_in[2];
    const float* beta  = (const float*)d_in[3];
    const float* rmean = (const float*)d_in[4];
    const float* rvar  = (const float*)d_in[5];
    float* out = (float*)d_out;

    msedge_kernel<<<dim3(NB * NPTS / ROWS), dim3(512), 0, stream>>>(
        x, W, gamma, beta, rmean, rvar, out);
}